// Round 9
// baseline (65.787 us; speedup 1.0000x reference)
//
#include <hip/hip_runtime.h>
#include <cstdint>

// CovNet BNN: out = clip(x @ sign(W1)^T + b1, ±1) @ W2^T + b2
// B=8192, IN=784, HID=4096, OUT=10.
// R9: m201-faithful 4-phase/K-tile. 16x16x32 frags (R8's verified low-conflict
// reads), A rows M-INTERLEAVED (row = MI*32 + wm*16, so MI 0..3 -> Ah0,
// MI 4..7 -> Ah1 for ALL waves), quadrants Gray over (mh,kk):
//   P0=(m0,k0): rd af[4]+bf0[4] (12.. 8 reads), P1=(m1,k0): rd af[4] (bf0 held),
//   P2=(m0,k1): rd af[4]+bf1[4], P3=(m1,k1): rd af[4] (bf1 held)  => 24/tile.
// Each phase: {reads; 2-op stage; bar1; lgkm0+schedbar; prio1; 16 MFMA; prio0;
// [vmcnt]; bar2} — m201's double-barrier pacing (phase LDS ~580cy ~ MFMA 620cy).
// Stage ledger (buf p^1): P0:Ah0(t+1) P1:Bh0(t+1) P2:Bh1(t+1) P3:Ah1(t+1).
//   P0-bar2 vmcnt(2): outstanding {Ah1(t),Ah0(t+1)}=4 -> certs Ah1(t) (P1's
//     reads), leaves Ah0(t+1).  [tail tt=NKT-1: vmcnt(0) certs Ah1(12)]
//   P3-bar2 vmcnt(2): outstanding {Ah0',Bh0',Bh1',Ah1'}=8 -> certs first 6
//     (all P0(t+1) needs), leaves Ah1(t+1) in flight. Never drains mid-loop.
//   Slacks: Ah0' 4 phases, Bh0' 3, Bh1' 2, Ah1' 2 — all >= ~1200cy > HBM 900.
// WAR: each stage overwrites data last read >=2 barriers earlier (audited).
// Prologue Ah0,Bh0,Bh1,Ah1(0); vmcnt(2); barrier -> steady state from tile 0.
// Epilogue = R3's verbatim (M-interleaved rows, passed at absmax 0.0625).

#define BATCH 8192
#define IN_F  784
#define HID   4096
#define OUT_F 10
#define KP    832     // padded K = 13*64
#define NKT   13
#define BM    256
#define BN    256
#define BK    64
#define NCT   (HID / BN)   // 16 col tiles
#define HCS   264          // epilogue hc row stride (f16)

typedef unsigned short u16;
typedef __attribute__((ext_vector_type(4))) unsigned short u16x4;
typedef __attribute__((ext_vector_type(8)))  _Float16 f16x8;
typedef __attribute__((ext_vector_type(4)))  float    f32x4;

#define BARRIER() do { asm volatile("" ::: "memory"); \
                       __builtin_amdgcn_s_barrier();  \
                       asm volatile("" ::: "memory"); } while (0)
#define WAITV(n)  asm volatile("s_waitcnt vmcnt(" #n ")" ::: "memory")
#define WAITL0()  do { asm volatile("s_waitcnt lgkmcnt(0)" ::: "memory"); \
                       __builtin_amdgcn_sched_barrier(0); } while (0)

__device__ __forceinline__ u16 f2h(float f) {
  union { _Float16 h; u16 u; } c;
  c.h = (_Float16)f;   // RNE
  return c.u;
}

__device__ __forceinline__ void gl_lds16(const void* g, void* l) {
  __builtin_amdgcn_global_load_lds(
      (const __attribute__((address_space(1))) uint32_t*)g,
      (__attribute__((address_space(3))) uint32_t*)l, 16, 0, 0);
}

// ---------------- prep: x -> f16 (padded), W1 -> sign f16 (padded), W2 -> [16][4096]
__global__ void prep_kernel(const float* __restrict__ x, const float* __restrict__ W1,
                            const float* __restrict__ W2,
                            u16* __restrict__ xh, u16* __restrict__ wh,
                            u16* __restrict__ w2h) {
  const int stride = gridDim.x * blockDim.x;
  const int gid = blockIdx.x * blockDim.x + threadIdx.x;
  const int KP4 = KP / 4;    // 208
  const int IN4 = IN_F / 4;  // 196
  const float4* x4 = (const float4*)x;
  const float4* w4 = (const float4*)W1;
  for (int i = gid; i < BATCH * KP4; i += stride) {
    int b = i / KP4, k = i - b * KP4;
    u16x4 o = {0, 0, 0, 0};
    if (k < IN4) {
      float4 v = x4[(size_t)b * IN4 + k];
      o[0] = f2h(v.x); o[1] = f2h(v.y); o[2] = f2h(v.z); o[3] = f2h(v.w);
    }
    *(u16x4*)&xh[(size_t)b * KP + k * 4] = o;
  }
  for (int i = gid; i < HID * KP4; i += stride) {
    int h = i / KP4, k = i - h * KP4;
    u16x4 o = {0, 0, 0, 0};
    if (k < IN4) {
      float4 v = w4[(size_t)h * IN4 + k];
      o[0] = v.x > 0.f ? 0x3C00 : (v.x < 0.f ? 0xBC00 : 0);
      o[1] = v.y > 0.f ? 0x3C00 : (v.y < 0.f ? 0xBC00 : 0);
      o[2] = v.z > 0.f ? 0x3C00 : (v.z < 0.f ? 0xBC00 : 0);
      o[3] = v.w > 0.f ? 0x3C00 : (v.w < 0.f ? 0xBC00 : 0);
    }
    *(u16x4*)&wh[(size_t)h * KP + k * 4] = o;
  }
  for (int i = gid; i < 16 * HID; i += stride) {
    int o = i >> 12, k = i & (HID - 1);
    w2h[i] = (o < OUT_F) ? f2h(W2[o * HID + k]) : (u16)0;
  }
}

// ---------------- main fused GEMM (256x256, 8 waves, 16x16x32, m201 4-phase)
__global__ void __launch_bounds__(512, 2) gemm_kernel(
    const u16* __restrict__ xh, const u16* __restrict__ wh,
    const u16* __restrict__ w2h, const float* __restrict__ b1,
    float* __restrict__ part) {
  __shared__ union {
    struct { u16 A[2][BM * BK]; u16 B[2][BN * BK]; } m;   // 128 KiB
    struct { u16 hc[128 * HCS]; u16 w2[16 * 256]; } e;    // ~74 KiB
  } sm;

  const int t   = threadIdx.x;
  const int ct  = blockIdx.x;   // col tile (HID), 0..15
  const int br  = blockIdx.y;   // row tile (BATCH), 0..31
  const int w   = t >> 6;       // wave 0..7
  const int l   = t & 63;
  const int wm  = w >> 2;       // A row = MI*32 + wm*16 + r16 (M interleave)
  const int wn  = w & 3;        // B col = wn*64 + nj*16 + r16
  const int g   = l >> 4;
  const int r16 = l & 15;
  const int swz = (r16 & 7) << 3;   // f16-unit XOR (16B-slot granule)

  // staging: thread t covers 16B; per 64-row chunk: row = t>>3; source slot
  // pre-swizzled (rule #21): logical slot = (t&7)^(row&7); LDS dest linear.
  const int  srow  = t >> 3;
  const int  sslot = (t & 7) ^ (srow & 7);
  const u16* gA = xh + (size_t)(br * BM) * KP + sslot * 8;
  const u16* gB = wh + (size_t)(ct * BN) * KP + sslot * 8;

  auto stA2 = [&](int tile, int h) {   // A half h = rows h*128..h*128+127 (2 ops)
    const int b = tile & 1;
#pragma unroll
    for (int c = 2 * h; c < 2 * h + 2; ++c)
      gl_lds16(gA + (size_t)(c * 64 + srow) * KP + tile * BK,
               &sm.m.A[b][c * 4096 + t * 8]);
  };
  auto stB2 = [&](int tile, int h) {   // B half h = cols h*128..h*128+127 (2 ops)
    const int b = tile & 1;
#pragma unroll
    for (int c = 2 * h; c < 2 * h + 2; ++c)
      gl_lds16(gB + (size_t)(c * 64 + srow) * KP + tile * BK,
               &sm.m.B[b][c * 4096 + t * 8]);
  };
  // reads apply the same XOR involution: phys slot = logical slot ^ (row&7)
  auto rdA = [&](int p, int MI, int kk) -> f16x8 {   // MI 0..7; 0..3 in Ah0
    int row = MI * 32 + wm * 16 + r16;
    return *(const f16x8*)&sm.m.A[p][row * 64 + ((kk * 32 + g * 8) ^ swz)];
  };
  auto rdB = [&](int p, int nj, int kk) -> f16x8 {   // col-chunk wn only
    int row = wn * 64 + nj * 16 + r16;
    return *(const f16x8*)&sm.m.B[p][row * 64 + ((kk * 32 + g * 8) ^ swz)];
  };

  f32x4 acc[8][4] = {};   // [MI][nj]
  f16x8 af[4], bf0[4], bf1[4];

#define MFMA16(MH, BF) do {                                           \
    __builtin_amdgcn_s_setprio(1);                                    \
    _Pragma("unroll") for (int mi_ = 0; mi_ < 4; ++mi_)               \
      _Pragma("unroll") for (int nj_ = 0; nj_ < 4; ++nj_)             \
        acc[(MH) * 4 + mi_][nj_] = __builtin_amdgcn_mfma_f32_16x16x32_f16( \
            af[mi_], BF[nj_], acc[(MH) * 4 + mi_][nj_], 0, 0, 0);     \
    __builtin_amdgcn_s_setprio(0);                                    \
  } while (0)

  // prologue: Ah0(0),Bh0(0),Bh1(0),Ah1(0); certify first 3, Ah1(0) flies
  stA2(0, 0); stB2(0, 0); stB2(0, 1); stA2(0, 1);
  WAITV(2);
  BARRIER();

  for (int tt = 0; tt < NKT; ++tt) {
    const int  p    = tt & 1;
    const bool more = (tt + 1 < NKT);

    // ---- P0: Q(m0,k0) — 8 reads ----
#pragma unroll
    for (int mi = 0; mi < 4; ++mi) af[mi] = rdA(p, mi, 0);
#pragma unroll
    for (int nj = 0; nj < 4; ++nj) bf0[nj] = rdB(p, nj, 0);
    if (more) stA2(tt + 1, 0);
    BARRIER();
    WAITL0();
    MFMA16(0, bf0);
    if (more) { WAITV(2); } else { WAITV(0); }   // certs Ah1(t) for P1 reads
    BARRIER();

    // ---- P1: Q(m1,k0) — 4 reads, bf0 held ----
#pragma unroll
    for (int mi = 0; mi < 4; ++mi) af[mi] = rdA(p, 4 + mi, 0);
    if (more) stB2(tt + 1, 0);
    BARRIER();
    WAITL0();
    MFMA16(1, bf0);
    BARRIER();

    // ---- P2: Q(m0,k1) — 8 reads ----
#pragma unroll
    for (int mi = 0; mi < 4; ++mi) af[mi] = rdA(p, mi, 1);
#pragma unroll
    for (int nj = 0; nj < 4; ++nj) bf1[nj] = rdB(p, nj, 1);
    if (more) stB2(tt + 1, 1);
    BARRIER();
    WAITL0();
    MFMA16(0, bf1);
    BARRIER();

    // ---- P3: Q(m1,k1) — 4 reads, bf1 held ----
#pragma unroll
    for (int mi = 0; mi < 4; ++mi) af[mi] = rdA(p, 4 + mi, 1);
    if (more) stA2(tt + 1, 1);
    BARRIER();
    WAITL0();
    MFMA16(1, bf1);
    if (more) WAITV(2);   // certs Ah0',Bh0',Bh1'(t+1); Ah1'(t+1) stays in flight
    BARRIER();
  }

  // ---- epilogue: h = clip(acc + b1), fused GEMM2 through LDS (R3 verbatim) ----
  WAITL0();
  BARRIER();   // e.* overlays m.A/m.B; all main-loop LDS traffic drained
  {
    int row = t >> 5, sp = t & 31;
    int ls = (sp & 24) | ((sp ^ row) & 7);   // swizzled logical slot
    gl_lds16(w2h + (size_t)row * HID + ct * BN + ls * 8, &sm.e.w2[t * 8]);
  }
  float b1v[4];
#pragma unroll
  for (int ni = 0; ni < 4; ++ni) b1v[ni] = b1[ct * BN + wn * 64 + ni * 16 + r16];

  float* partBase = part + ((size_t)ct * BATCH + br * BM) * 16;

#pragma unroll
  for (int p = 0; p < 2; ++p) {
    if (p == 1) BARRIER();               // p=0 hc reads done before overwrite
    // pass p writes global rows [p*128,+128) = acc[p*4+mi][*];
    // local hc row = mi*32 + wm*16 + g*4 + r  (M-interleaved mapping)
#pragma unroll
    for (int mi = 0; mi < 4; ++mi)
#pragma unroll
      for (int ni = 0; ni < 4; ++ni)
#pragma unroll
        for (int r = 0; r < 4; ++r) {
          float v = acc[p * 4 + mi][ni][r] + b1v[ni];
          v = fminf(fmaxf(v, -1.f), 1.f);
          sm.e.hc[(mi * 32 + wm * 16 + g * 4 + r) * HCS + wn * 64 + ni * 16 + r16] = f2h(v);
        }
    if (p == 0) { WAITV(0); }            // w2 landed
    BARRIER();
    f32x4 acc2 = {};
#pragma unroll
    for (int kk = 0; kk < 8; ++kk) {
      f16x8 a2 = *(const f16x8*)&sm.e.hc[(w * 16 + r16) * HCS + kk * 32 + g * 8];
      int s   = kk * 4 + g;
      int sp2 = (s & 24) | ((s ^ r16) & 7);
      f16x8 b2f = *(const f16x8*)&sm.e.w2[r16 * 256 + sp2 * 8];
      acc2 = __builtin_amdgcn_mfma_f32_16x16x32_f16(a2, b2f, acc2, 0, 0, 0);
    }
#pragma unroll
    for (int r = 0; r < 4; ++r)
      partBase[(size_t)(p * 128 + w * 16 + g * 4 + r) * 16 + r16] = acc2[r];
  }
}

// ---------------- reduce partials over 16 col tiles + b2
__global__ void reduce_kernel(const float* __restrict__ part, const float* __restrict__ b2,
                              float* __restrict__ out) {
  int i = blockIdx.x * blockDim.x + threadIdx.x;
  if (i >= BATCH * OUT_F) return;
  int b = i / OUT_F, o = i - b * OUT_F;
  float acc = b2[o];
#pragma unroll
  for (int c = 0; c < NCT; ++c)
    acc += part[((size_t)c * BATCH + b) * 16 + o];
  out[i] = acc;
}

extern "C" void kernel_launch(void* const* d_in, const int* in_sizes, int n_in,
                              void* d_out, int out_size, void* d_ws, size_t ws_size,
                              hipStream_t stream) {
  const float* x  = (const float*)d_in[0];
  const float* W1 = (const float*)d_in[1];
  const float* b1 = (const float*)d_in[2];
  const float* W2 = (const float*)d_in[3];
  const float* b2 = (const float*)d_in[4];
  float* out = (float*)d_out;

  // ws layout (~29 MB): xh 13.6 MB | wh 6.8 MB | w2h 0.13 MB | part 8.4 MB
  u16* xh  = (u16*)d_ws;
  u16* wh  = xh + (size_t)BATCH * KP;
  u16* w2h = wh + (size_t)HID * KP;
  float* part = (float*)(w2h + 16 * HID);

  hipLaunchKernelGGL(prep_kernel, dim3(2048), dim3(256), 0, stream, x, W1, W2, xh, wh, w2h);
  hipLaunchKernelGGL(gemm_kernel, dim3(NCT, BATCH / BM), dim3(512), 0, stream,
                     xh, wh, w2h, b1, part);
  hipLaunchKernelGGL(reduce_kernel, dim3((BATCH * OUT_F + 255) / 256), dim3(256), 0, stream,
                     part, b2, out);
}